// Round 7
// baseline (220.721 us; speedup 1.0000x reference)
//
#include <hip/hip_runtime.h>
#include <hip/hip_bf16.h>
#include <math.h>

// Problem constants (match reference setup_inputs)
#define T_N   400      // NTHETA
#define Z_N   128      // NZ
#define XY_N  16384    // NX*NY
#define NCPLX (3 * XY_N * Z_N)          // 6291456 complex elements
#define A_CONST 5.905249382768714f      // pi / 0.532

// Output-format hypotheses, dispatched at runtime on out_size:
//  OUT_F32_REAL  : out_size == NCPLX      -> float*, real part only (astype(f32) of complex)
//  OUT_BF16_PLANAR: out_size == 2*NCPLX   -> bf16*, [re-plane][im-plane] (interleaved falsified in R4)
//  OUT_F32_PAIR  : out_size >= 2*NCPLX f32 -> float*, interleaved (re,im) view (falsified by R5 crash; kept for safety)
#define OUT_F32_REAL    0
#define OUT_BF16_PLANAR 1
#define OUT_F32_PAIR    2

// ---------------------------------------------------------------------------
// Kernel 1 (fast path): kern[t][z] = w[t]*exp(i*(abbr[t] - U[z]*cos(theta[t])))
// float2 in workspace, 400*128 = 409.6 KB. Only launched if ws_size >= that.
// ---------------------------------------------------------------------------
__global__ __launch_bounds__(256) void kern_build(
    const float* __restrict__ abbr,
    const float* __restrict__ theta,
    const float* __restrict__ U,
    float2* __restrict__ kern)
{
    int idx = blockIdx.x * blockDim.x + threadIdx.x;
    if (idx >= T_N * Z_N) return;
    int z = idx & (Z_N - 1);
    int t = idx >> 7;

    float th = theta[t];
    float w;
    if (t == 0)              w = 0.5f * (theta[1] - theta[0]);
    else if (t == T_N - 1)   w = 0.5f * (theta[T_N - 1] - theta[T_N - 2]);
    else                     w = 0.5f * (theta[t + 1] - theta[t - 1]);

    float ct  = cosf(th);
    float ang = abbr[t] - U[z] * ct;
    float s, c;
    sincosf(ang, &s, &c);
    kern[idx] = make_float2(c * w, s * w);
}

// ---------------------------------------------------------------------------
// Main kernel: per block 8 xy rows x 128 z. Func rows staged in LDS as
// [t][comp(3)][row(8)]; inner loop: 3 broadcast float4 LDS reads + kern + 24 FMA.
// PRECOMP=true reads kern from workspace; false computes it inline (no ws use).
// MODE selects the output byte format (see above); all modes write exactly
// out_size elements -> no OOB possible on any hypothesis.
// ---------------------------------------------------------------------------
template <bool PRECOMP, int MODE>
__global__ __launch_bounds__(256) void psf_main(
    const float* __restrict__ F0,
    const float* __restrict__ F1,
    const float* __restrict__ F2,
    const float* __restrict__ Phi,
    const float2* __restrict__ kern,
    const float* __restrict__ abbr,
    const float* __restrict__ theta,
    const float* __restrict__ U,
    void* __restrict__ outv)
{
    __shared__ float flds[T_N * 24];   // 38400 B
    __shared__ float ct_s[T_N];        // used only when !PRECOMP
    __shared__ float ear_s[T_N];
    __shared__ float eai_s[T_N];

    const int z   = threadIdx.x;       // 0..127
    const int ty  = threadIdx.y;       // 0..1
    const int tid = ty * 128 + z;
    const int xy0 = blockIdx.x * 8;

    if constexpr (!PRECOMP) {
        for (int t = tid; t < T_N; t += 256) {
            float th = theta[t];
            float w;
            if (t == 0)              w = 0.5f * (theta[1] - theta[0]);
            else if (t == T_N - 1)   w = 0.5f * (theta[T_N - 1] - theta[T_N - 2]);
            else                     w = 0.5f * (theta[t + 1] - theta[t - 1]);
            ct_s[t] = cosf(th);
            float s, c;
            sincosf(abbr[t], &s, &c);
            ear_s[t] = c * w;
            eai_s[t] = s * w;
        }
    }

    // Stage Func rows: li -> (t fastest) for coalesced global reads
    for (int li = tid; li < T_N * 24; li += 256) {
        int t  = li % T_N;
        int rc = li / T_N;
        int r  = rc & 7;
        int c  = rc >> 3;
        const float* __restrict__ F = (c == 0) ? F0 : (c == 1) ? F1 : F2;
        flds[t * 24 + c * 8 + r] = F[(xy0 + r) * T_N + t];
    }
    __syncthreads();

    const float Uz = U[z];

    float a0re[4] = {0.f,0.f,0.f,0.f}, a0im[4] = {0.f,0.f,0.f,0.f};
    float a1re[4] = {0.f,0.f,0.f,0.f}, a1im[4] = {0.f,0.f,0.f,0.f};
    float a2re[4] = {0.f,0.f,0.f,0.f}, a2im[4] = {0.f,0.f,0.f,0.f};

    const int rbase = ty * 4;

    for (int t = 0; t < T_N; ++t) {
        float2 k;
        if constexpr (PRECOMP) {
            k = kern[t * Z_N + z];                  // coalesced, L2-resident
        } else {
            float ang = Uz * ct_s[t];
            float cs = __cosf(ang);
            float sn = __sinf(ang);
            float er = ear_s[t], ei = eai_s[t];
            k.x = er * cs + ei * sn;                // (er+i*ei)*(cs-i*sn)
            k.y = ei * cs - er * sn;
        }
        float4 f0 = *(const float4*)&flds[t * 24 + 0 * 8 + rbase];
        float4 f1 = *(const float4*)&flds[t * 24 + 1 * 8 + rbase];
        float4 f2 = *(const float4*)&flds[t * 24 + 2 * 8 + rbase];

        a0re[0] += f0.x * k.x;  a0im[0] += f0.x * k.y;
        a0re[1] += f0.y * k.x;  a0im[1] += f0.y * k.y;
        a0re[2] += f0.z * k.x;  a0im[2] += f0.z * k.y;
        a0re[3] += f0.w * k.x;  a0im[3] += f0.w * k.y;

        a1re[0] += f1.x * k.x;  a1im[0] += f1.x * k.y;
        a1re[1] += f1.y * k.x;  a1im[1] += f1.y * k.y;
        a1re[2] += f1.z * k.x;  a1im[2] += f1.z * k.y;
        a1re[3] += f1.w * k.x;  a1im[3] += f1.w * k.y;

        a2re[0] += f2.x * k.x;  a2im[0] += f2.x * k.y;
        a2re[1] += f2.y * k.x;  a2im[1] += f2.y * k.y;
        a2re[2] += f2.z * k.x;  a2im[2] += f2.z * k.y;
        a2re[3] += f2.w * k.x;  a2im[3] += f2.w * k.y;
    }

    // Epilogue: Phi factors, write per MODE.
#pragma unroll
    for (int r = 0; r < 4; ++r) {
        int xy = xy0 + rbase + r;
        float p = Phi[xy];
        float sp, cp;
        sincosf(p, &sp, &cp);
        float c2p = cp * cp - sp * sp;
        float s2p = 2.f * sp * cp;

        // Ex = i*A*(I0 + I2*cos2p); Ey = i*A*I2*sin2p; Ez = -2A*I1*cosp
        float ex_re = -A_CONST * (a0im[r] + a2im[r] * c2p);
        float ex_im =  A_CONST * (a0re[r] + a2re[r] * c2p);
        float ey_re = -A_CONST * a2im[r] * s2p;
        float ey_im =  A_CONST * a2re[r] * s2p;
        float ez_re = -2.f * A_CONST * a1re[r] * cp;
        float ez_im = -2.f * A_CONST * a1im[r] * cp;

        const int i0 = (0 * XY_N + xy) * Z_N + z;
        const int i1 = (1 * XY_N + xy) * Z_N + z;
        const int i2 = (2 * XY_N + xy) * Z_N + z;

        if constexpr (MODE == OUT_F32_REAL) {
            float* o = (float*)outv;           // 6.29M f32: real part only
            o[i0] = ex_re;
            o[i1] = ey_re;
            o[i2] = ez_re;
        } else if constexpr (MODE == OUT_BF16_PLANAR) {
            __hip_bfloat16* o = (__hip_bfloat16*)outv;   // 12.58M bf16: [re-plane][im-plane]
            o[i0]         = __float2bfloat16(ex_re);
            o[NCPLX + i0] = __float2bfloat16(ex_im);
            o[i1]         = __float2bfloat16(ey_re);
            o[NCPLX + i1] = __float2bfloat16(ey_im);
            o[i2]         = __float2bfloat16(ez_re);
            o[NCPLX + i2] = __float2bfloat16(ez_im);
        } else {
            float2* o = (float2*)outv;         // 12.58M f32: interleaved (re,im)
            o[i0] = make_float2(ex_re, ex_im);
            o[i1] = make_float2(ey_re, ey_im);
            o[i2] = make_float2(ez_re, ez_im);
        }
    }
}

extern "C" void kernel_launch(void* const* d_in, const int* in_sizes, int n_in,
                              void* d_out, int out_size, void* d_ws, size_t ws_size,
                              hipStream_t stream) {
    const float* abbr  = (const float*)d_in[0];
    const float* F0    = (const float*)d_in[1];
    const float* F1    = (const float*)d_in[2];
    const float* F2    = (const float*)d_in[3];
    const float* Phi   = (const float*)d_in[4];
    const float* theta = (const float*)d_in[5];
    const float* U     = (const float*)d_in[6];

    const size_t kern_bytes = (size_t)T_N * Z_N * sizeof(float2);
    const bool precomp = (d_ws != nullptr && ws_size >= kern_bytes);
    float2* kern = (float2*)d_ws;
    dim3 blk(128, 2, 1);

    if (precomp) {
        kern_build<<<(T_N * Z_N + 255) / 256, 256, 0, stream>>>(abbr, theta, U, kern);
    }

    // Runtime dispatch on the actual output element count (see header comment).
    int mode;
    if (out_size == NCPLX)            mode = OUT_F32_REAL;     // 6,291,456 f32
    else if (out_size == 2 * NCPLX)   mode = OUT_BF16_PLANAR;  // 12,582,912 bf16
    else if (out_size >= 2 * NCPLX)   mode = OUT_F32_PAIR;     // 12,582,912 f32 (>=50.3MB)
    else                              mode = OUT_F32_REAL;     // smallest-footprint fallback

    #define LAUNCH(P, M) psf_main<P, M><<<XY_N / 8, blk, 0, stream>>>( \
        F0, F1, F2, Phi, kern, abbr, theta, U, d_out)
    if (precomp) {
        if (mode == OUT_F32_REAL)          LAUNCH(true,  OUT_F32_REAL);
        else if (mode == OUT_BF16_PLANAR)  LAUNCH(true,  OUT_BF16_PLANAR);
        else                               LAUNCH(true,  OUT_F32_PAIR);
    } else {
        if (mode == OUT_F32_REAL)          LAUNCH(false, OUT_F32_REAL);
        else if (mode == OUT_BF16_PLANAR)  LAUNCH(false, OUT_BF16_PLANAR);
        else                               LAUNCH(false, OUT_F32_PAIR);
    }
    #undef LAUNCH
}

// Round 9
// 154.717 us; speedup vs baseline: 1.4266x; 1.4266x over previous
//
#include <hip/hip_runtime.h>
#include <hip/hip_bf16.h>
#include <math.h>

// Problem constants (match reference setup_inputs)
#define T_N   400      // NTHETA
#define K_PAD 416      // 13 * 32 (MFMA K-steps), padded with zero kern
#define Z_N   128      // NZ
#define XY_N  16384    // NX*NY
#define NCPLX (3 * XY_N * Z_N)          // 6291456 = confirmed out_size (f32, real part)
#define A_CONST 5.905249382768714f      // pi / 0.532

typedef short  bf16x8 __attribute__((ext_vector_type(8)));
typedef float  f32x4  __attribute__((ext_vector_type(4)));

static __device__ __forceinline__ short f2bf(float f) {
    __hip_bfloat16 h = __float2bfloat16(f);
    return *reinterpret_cast<short*>(&h);
}

// ---------------------------------------------------------------------------
// Build B in ws: kernBT[p][z][k] bf16; p=0: w*cos(ang), p=1: w*sin(ang),
// ang = abbr[k] - U[z]*cos(theta[k]); k in [400,416) -> 0 (zero-pad).
// Size: 2*128*416*2B = 212992 B.
// ---------------------------------------------------------------------------
__global__ __launch_bounds__(256) void kern_build_bf16(
    const float* __restrict__ abbr,
    const float* __restrict__ theta,
    const float* __restrict__ U,
    __hip_bfloat16* __restrict__ kernBT)
{
    int idx = blockIdx.x * 256 + threadIdx.x;    // (p*128 + z)*K_PAD + k
    if (idx >= 2 * Z_N * K_PAD) return;
    int k  = idx % K_PAD;
    int pz = idx / K_PAD;
    int z  = pz & 127;
    int p  = pz >> 7;

    float val = 0.f;
    if (k < T_N) {
        float th = theta[k];
        float w;
        if (k == 0)            w = 0.5f * (theta[1] - theta[0]);
        else if (k == T_N - 1) w = 0.5f * (theta[T_N - 1] - theta[T_N - 2]);
        else                   w = 0.5f * (theta[k + 1] - theta[k - 1]);
        float ang = abbr[k] - U[z] * cosf(th);
        val = w * ((p == 0) ? cosf(ang) : sinf(ang));
    }
    kernBT[idx] = __float2bfloat16(val);
}

// ---------------------------------------------------------------------------
// MFMA main: 3 real GEMMs (I0im = F0*kern_im, I1re = F1*kern_re, I2im = F2*kern_im)
// fused with the Phi epilogue. No LDS, no barriers.
// Wave w (2048 total): rows Rtile = (W>>1)*16 (16 rows), z-half zb = (W&1)*64.
// Per k-step: 3 A-frags (f32x8 -> bf16, reg), 8 B-frags (bf16 from L2), 12 MFMA.
// A frag (16x16x32): lane l holds A[row=l&15][k=kb+(l>>4)*8 + 0..7]
// B frag:            lane l holds B[k=kb+(l>>4)*8 + 0..7][col=l&15]
// C frag:            col=l&15, row=(l>>4)*4 + reg   [guide §3, m89-verified]
// ---------------------------------------------------------------------------
__global__ __launch_bounds__(256) void psf_mfma(
    const float* __restrict__ F0,
    const float* __restrict__ F1,
    const float* __restrict__ F2,
    const float* __restrict__ Phi,
    const __hip_bfloat16* __restrict__ kernBT,
    float* __restrict__ out)
{
    const int tid   = threadIdx.x;
    const int l     = tid & 63;
    const int wave  = tid >> 6;
    const int W     = blockIdx.x * 4 + wave;
    const int R     = (W >> 1) << 4;         // row-tile base (16 rows)
    const int zb    = (W & 1) << 6;          // z-half base: 0 or 64

    const int arow  = R + (l & 15);          // A-frag row for this lane
    const int chunk = (l >> 4) * 8;          // k-chunk offset within k-step
    const int zcol  = zb + (l & 15);         // B-frag z-col base (+ zt*16)

    f32x4 acc[3][4];
#pragma unroll
    for (int c = 0; c < 3; ++c)
#pragma unroll
        for (int zt = 0; zt < 4; ++zt) acc[c][zt] = (f32x4){0.f, 0.f, 0.f, 0.f};

#pragma unroll 1
    for (int ks = 0; ks < 13; ++ks) {
        const int kbase = ks * 32;
        const int kk    = kbase + chunk;
        const int ksrc  = (kk < T_N) ? kk : 0;   // tail: clamp addr, kern=0 kills it

        // --- A fragments: 32B f32 load + convert, per component ---
        bf16x8 afr[3];
        {
            const size_t rbase = (size_t)arow * T_N + ksrc;
            const float* ap0 = F0 + rbase;
            const float* ap1 = F1 + rbase;
            const float* ap2 = F2 + rbase;
#pragma unroll
            for (int c = 0; c < 3; ++c) {
                const float* ap = (c == 0) ? ap0 : (c == 1) ? ap1 : ap2;
                float4 lo = *(const float4*)ap;
                float4 hi = *(const float4*)(ap + 4);
                bf16x8 a;
                a[0] = f2bf(lo.x); a[1] = f2bf(lo.y); a[2] = f2bf(lo.z); a[3] = f2bf(lo.w);
                a[4] = f2bf(hi.x); a[5] = f2bf(hi.y); a[6] = f2bf(hi.z); a[7] = f2bf(hi.w);
                afr[c] = a;
            }
        }

        // --- B fragments: 16B bf16 loads, L2-resident (213 KB total) ---
        bf16x8 bfr[2][4];
#pragma unroll
        for (int p = 0; p < 2; ++p)
#pragma unroll
            for (int zt = 0; zt < 4; ++zt) {
                const __hip_bfloat16* bp =
                    kernBT + (size_t)(p * Z_N + zcol + zt * 16) * K_PAD + kbase + chunk;
                bfr[p][zt] = *(const bf16x8*)bp;
            }

        // --- 12 MFMAs: comp0 (F0 x im), comp1 (F1 x re), comp2 (F2 x im) ---
#pragma unroll
        for (int c = 0; c < 3; ++c) {
            const int p = (c == 1) ? 0 : 1;
#pragma unroll
            for (int zt = 0; zt < 4; ++zt)
                acc[c][zt] = __builtin_amdgcn_mfma_f32_16x16x32_bf16(
                    afr[c], bfr[p][zt], acc[c][zt], 0, 0, 0);
        }
    }

    // --- Epilogue: Re(Ex) = -A*(I0im + I2im*cos2p); Re(Ey) = -A*I2im*sin2p;
    //               Re(Ez) = -2A*I1re*cosp ---
    const int xyb = R + (l >> 4) * 4;
#pragma unroll
    for (int r = 0; r < 4; ++r) {
        const int xy = xyb + r;
        float ph = Phi[xy];
        float sp, cp;
        sincosf(ph, &sp, &cp);
        const float c2p = cp * cp - sp * sp;
        const float s2p = 2.f * sp * cp;
#pragma unroll
        for (int zt = 0; zt < 4; ++zt) {
            const int z = zb + zt * 16 + (l & 15);
            out[(0 * XY_N + xy) * Z_N + z] = -A_CONST * (acc[0][zt][r] + acc[2][zt][r] * c2p);
            out[(1 * XY_N + xy) * Z_N + z] = -A_CONST * acc[2][zt][r] * s2p;
            out[(2 * XY_N + xy) * Z_N + z] = -2.f * A_CONST * acc[1][zt][r] * cp;
        }
    }
}

// ===========================================================================
// Fallback path (proven in R7): f32 vector kernel, handles any out_size/ws_size.
// ===========================================================================
#define OUT_F32_REAL    0
#define OUT_BF16_PLANAR 1
#define OUT_F32_PAIR    2

__global__ __launch_bounds__(256) void kern_build(
    const float* __restrict__ abbr,
    const float* __restrict__ theta,
    const float* __restrict__ U,
    float2* __restrict__ kern)
{
    int idx = blockIdx.x * blockDim.x + threadIdx.x;
    if (idx >= T_N * Z_N) return;
    int z = idx & (Z_N - 1);
    int t = idx >> 7;
    float th = theta[t];
    float w;
    if (t == 0)              w = 0.5f * (theta[1] - theta[0]);
    else if (t == T_N - 1)   w = 0.5f * (theta[T_N - 1] - theta[T_N - 2]);
    else                     w = 0.5f * (theta[t + 1] - theta[t - 1]);
    float ct  = cosf(th);
    float ang = abbr[t] - U[z] * ct;
    float s, c;
    sincosf(ang, &s, &c);
    kern[idx] = make_float2(c * w, s * w);
}

template <bool PRECOMP, int MODE>
__global__ __launch_bounds__(256) void psf_main(
    const float* __restrict__ F0, const float* __restrict__ F1,
    const float* __restrict__ F2, const float* __restrict__ Phi,
    const float2* __restrict__ kern, const float* __restrict__ abbr,
    const float* __restrict__ theta, const float* __restrict__ U,
    void* __restrict__ outv)
{
    __shared__ float flds[T_N * 24];
    __shared__ float ct_s[T_N];
    __shared__ float ear_s[T_N];
    __shared__ float eai_s[T_N];

    const int z   = threadIdx.x;
    const int ty  = threadIdx.y;
    const int tid = ty * 128 + z;
    const int xy0 = blockIdx.x * 8;

    if constexpr (!PRECOMP) {
        for (int t = tid; t < T_N; t += 256) {
            float th = theta[t];
            float w;
            if (t == 0)              w = 0.5f * (theta[1] - theta[0]);
            else if (t == T_N - 1)   w = 0.5f * (theta[T_N - 1] - theta[T_N - 2]);
            else                     w = 0.5f * (theta[t + 1] - theta[t - 1]);
            ct_s[t] = cosf(th);
            float s, c;
            sincosf(abbr[t], &s, &c);
            ear_s[t] = c * w;
            eai_s[t] = s * w;
        }
    }
    for (int li = tid; li < T_N * 24; li += 256) {
        int t  = li % T_N;
        int rc = li / T_N;
        int r  = rc & 7;
        int c  = rc >> 3;
        const float* __restrict__ F = (c == 0) ? F0 : (c == 1) ? F1 : F2;
        flds[t * 24 + c * 8 + r] = F[(xy0 + r) * T_N + t];
    }
    __syncthreads();

    const float Uz = U[z];
    float a0re[4] = {0,0,0,0}, a0im[4] = {0,0,0,0};
    float a1re[4] = {0,0,0,0}, a1im[4] = {0,0,0,0};
    float a2re[4] = {0,0,0,0}, a2im[4] = {0,0,0,0};
    const int rbase = ty * 4;

    for (int t = 0; t < T_N; ++t) {
        float2 k;
        if constexpr (PRECOMP) {
            k = kern[t * Z_N + z];
        } else {
            float ang = Uz * ct_s[t];
            float cs = __cosf(ang), sn = __sinf(ang);
            float er = ear_s[t], ei = eai_s[t];
            k.x = er * cs + ei * sn;
            k.y = ei * cs - er * sn;
        }
        float4 f0 = *(const float4*)&flds[t * 24 + 0 * 8 + rbase];
        float4 f1 = *(const float4*)&flds[t * 24 + 1 * 8 + rbase];
        float4 f2 = *(const float4*)&flds[t * 24 + 2 * 8 + rbase];
        a0re[0]+=f0.x*k.x; a0im[0]+=f0.x*k.y; a0re[1]+=f0.y*k.x; a0im[1]+=f0.y*k.y;
        a0re[2]+=f0.z*k.x; a0im[2]+=f0.z*k.y; a0re[3]+=f0.w*k.x; a0im[3]+=f0.w*k.y;
        a1re[0]+=f1.x*k.x; a1im[0]+=f1.x*k.y; a1re[1]+=f1.y*k.x; a1im[1]+=f1.y*k.y;
        a1re[2]+=f1.z*k.x; a1im[2]+=f1.z*k.y; a1re[3]+=f1.w*k.x; a1im[3]+=f1.w*k.y;
        a2re[0]+=f2.x*k.x; a2im[0]+=f2.x*k.y; a2re[1]+=f2.y*k.x; a2im[1]+=f2.y*k.y;
        a2re[2]+=f2.z*k.x; a2im[2]+=f2.z*k.y; a2re[3]+=f2.w*k.x; a2im[3]+=f2.w*k.y;
    }

#pragma unroll
    for (int r = 0; r < 4; ++r) {
        int xy = xy0 + rbase + r;
        float p = Phi[xy];
        float sp, cp;
        sincosf(p, &sp, &cp);
        float c2p = cp * cp - sp * sp;
        float s2p = 2.f * sp * cp;
        float ex_re = -A_CONST * (a0im[r] + a2im[r] * c2p);
        float ex_im =  A_CONST * (a0re[r] + a2re[r] * c2p);
        float ey_re = -A_CONST * a2im[r] * s2p;
        float ey_im =  A_CONST * a2re[r] * s2p;
        float ez_re = -2.f * A_CONST * a1re[r] * cp;
        float ez_im = -2.f * A_CONST * a1im[r] * cp;
        const int i0 = (0 * XY_N + xy) * Z_N + z;
        const int i1 = (1 * XY_N + xy) * Z_N + z;
        const int i2 = (2 * XY_N + xy) * Z_N + z;
        if constexpr (MODE == OUT_F32_REAL) {
            float* o = (float*)outv;
            o[i0] = ex_re; o[i1] = ey_re; o[i2] = ez_re;
        } else if constexpr (MODE == OUT_BF16_PLANAR) {
            __hip_bfloat16* o = (__hip_bfloat16*)outv;
            o[i0] = __float2bfloat16(ex_re); o[NCPLX + i0] = __float2bfloat16(ex_im);
            o[i1] = __float2bfloat16(ey_re); o[NCPLX + i1] = __float2bfloat16(ey_im);
            o[i2] = __float2bfloat16(ez_re); o[NCPLX + i2] = __float2bfloat16(ez_im);
        } else {
            float2* o = (float2*)outv;
            o[i0] = make_float2(ex_re, ex_im);
            o[i1] = make_float2(ey_re, ey_im);
            o[i2] = make_float2(ez_re, ez_im);
        }
    }
}

extern "C" void kernel_launch(void* const* d_in, const int* in_sizes, int n_in,
                              void* d_out, int out_size, void* d_ws, size_t ws_size,
                              hipStream_t stream) {
    const float* abbr  = (const float*)d_in[0];
    const float* F0    = (const float*)d_in[1];
    const float* F1    = (const float*)d_in[2];
    const float* F2    = (const float*)d_in[3];
    const float* Phi   = (const float*)d_in[4];
    const float* theta = (const float*)d_in[5];
    const float* U     = (const float*)d_in[6];

    const size_t kernBT_bytes = (size_t)2 * Z_N * K_PAD * sizeof(__hip_bfloat16); // 212992

    if (out_size == NCPLX && d_ws != nullptr && ws_size >= kernBT_bytes) {
        // Fast path: bf16 MFMA, real-part-only output (confirmed by R7 counters).
        __hip_bfloat16* kernBT = (__hip_bfloat16*)d_ws;
        kern_build_bf16<<<(2 * Z_N * K_PAD + 255) / 256, 256, 0, stream>>>(
            abbr, theta, U, kernBT);
        psf_mfma<<<512, 256, 0, stream>>>(F0, F1, F2, Phi, kernBT, (float*)d_out);
        return;
    }

    // Fallback: proven R7 f32 path.
    const size_t kern_bytes = (size_t)T_N * Z_N * sizeof(float2);
    const bool precomp = (d_ws != nullptr && ws_size >= kern_bytes);
    float2* kern = (float2*)d_ws;
    dim3 blk(128, 2, 1);
    if (precomp)
        kern_build<<<(T_N * Z_N + 255) / 256, 256, 0, stream>>>(abbr, theta, U, kern);

    int mode;
    if (out_size == NCPLX)          mode = OUT_F32_REAL;
    else if (out_size == 2 * NCPLX) mode = OUT_BF16_PLANAR;
    else if (out_size > 2 * NCPLX)  mode = OUT_F32_PAIR;
    else                            mode = OUT_F32_REAL;

    #define LAUNCH(P, M) psf_main<P, M><<<XY_N / 8, blk, 0, stream>>>( \
        F0, F1, F2, Phi, kern, abbr, theta, U, d_out)
    if (precomp) {
        if (mode == OUT_F32_REAL)         LAUNCH(true,  OUT_F32_REAL);
        else if (mode == OUT_BF16_PLANAR) LAUNCH(true,  OUT_BF16_PLANAR);
        else                              LAUNCH(true,  OUT_F32_PAIR);
    } else {
        if (mode == OUT_F32_REAL)         LAUNCH(false, OUT_F32_REAL);
        else if (mode == OUT_BF16_PLANAR) LAUNCH(false, OUT_BF16_PLANAR);
        else                              LAUNCH(false, OUT_F32_PAIR);
    }
    #undef LAUNCH
}